// Round 6
// baseline (172.807 us; speedup 1.0000x reference)
//
#include <hip/hip_runtime.h>

// GAE scan: T=2048, N=4096, fp32. Chunked linear-recurrence scan, 2 kernels:
//   K1: per-(chunk, env2) compose affine: adv_at_chunk_top = P + A*adv_from_above
//   K2: per-(chunk, env2): coalesced L2-hot look-back over chunk summaries above
//       (b = A*b + P), then replay the chunk writing advantages and returns.
// N_CHUNKS=128, float2 over envs: 262144 threads/kernel = 4096 waves =
// 16 waves/CU (float4/C=128 gave only 8 waves/CU -> ~3.9 TB/s, latency-bound).
// Outputs stored non-temporally so the 67 MB write stream doesn't evict the
// L3-warm inputs / L2-resident A,P.
// NOTE: __builtin_nontemporal_store needs a clang vector type, not HIP's
// float2 class -> use ext_vector_type(2) throughout.

#define T_LEN    2048
#define N_ENV    4096
#define NV2      (N_ENV / 2)          // 2048 float2 columns
#define N_CHUNKS 128
#define CHUNK_L  (T_LEN / N_CHUNKS)   // 16

typedef float v2f __attribute__((ext_vector_type(2)));

static constexpr float GAMMA = 0.99f;
static constexpr float GL    = 0.99f * 0.95f;   // gamma * gae_lambda

__global__ __launch_bounds__(256) void gae_phase1(
    const v2f* __restrict__ rewards,   // [T_LEN][NV2]
    const v2f* __restrict__ values,
    const v2f* __restrict__ dones,
    v2f* __restrict__ Aout,            // [N_CHUNKS][NV2]
    v2f* __restrict__ Pout)
{
    const int idx = blockIdx.x * blockDim.x + threadIdx.x;   // c*NV2 + n2
    const int n2 = idx & (NV2 - 1);
    const int c  = idx >> 11;
    const int t_hi = c * CHUNK_L + (CHUNK_L - 1);

    v2f v_next, d_next;
    if (c == N_CHUNKS - 1) {
        v_next = (v2f)(0.f, 0.f);
        d_next = (v2f)(1.f, 1.f);
    } else {
        v_next = values[(t_hi + 1) * NV2 + n2];
        d_next = dones [(t_hi + 1) * NV2 + n2];
    }

    v2f A = (v2f)(1.f, 1.f);
    v2f P = (v2f)(0.f, 0.f);

    #pragma unroll
    for (int i = 0; i < CHUNK_L; ++i) {
        const int t = t_hi - i;
        const v2f r = rewards[t * NV2 + n2];
        const v2f v = values [t * NV2 + n2];
        const v2f d = dones  [t * NV2 + n2];
        #define STEP(X) { \
            const float nt    = 1.0f - d_next.X; \
            const float delta = fmaf(GAMMA * v_next.X, nt, r.X) - v.X; \
            const float cc    = GL * nt; \
            P.X = fmaf(cc, P.X, delta); \
            A.X = cc * A.X; \
            v_next.X = v.X; d_next.X = d.X; }
        STEP(x) STEP(y)
        #undef STEP
    }
    Aout[idx] = A;
    Pout[idx] = P;
}

__global__ __launch_bounds__(256) void gae_phase23(
    const v2f* __restrict__ rewards,
    const v2f* __restrict__ values,
    const v2f* __restrict__ dones,
    const v2f* __restrict__ Ain,    // [N_CHUNKS][NV2]
    const v2f* __restrict__ Pin,
    v2f* __restrict__ out)          // [2*T_LEN][NV2]: advantages then returns
{
    const int idx = blockIdx.x * blockDim.x + threadIdx.x;
    const int n2 = idx & (NV2 - 1);
    const int c  = idx >> 11;
    const int t_hi = c * CHUNK_L + (CHUNK_L - 1);

    // Coalesced look-back: incoming adv = suffix composition of chunk affines
    // above this chunk, applied to 0. A/P are 2 MB each -> L2-resident.
    v2f adv = (v2f)(0.f, 0.f);
    #pragma unroll 8
    for (int c2 = N_CHUNKS - 1; c2 > c; --c2) {
        const v2f a = Ain[c2 * NV2 + n2];
        const v2f p = Pin[c2 * NV2 + n2];
        adv.x = fmaf(a.x, adv.x, p.x);
        adv.y = fmaf(a.y, adv.y, p.y);
    }

    v2f v_next, d_next;
    if (c == N_CHUNKS - 1) {
        v_next = (v2f)(0.f, 0.f);
        d_next = (v2f)(1.f, 1.f);
    } else {
        v_next = values[(t_hi + 1) * NV2 + n2];
        d_next = dones [(t_hi + 1) * NV2 + n2];
    }

    #pragma unroll
    for (int i = 0; i < CHUNK_L; ++i) {
        const int t = t_hi - i;
        const v2f r = rewards[t * NV2 + n2];
        const v2f v = values [t * NV2 + n2];
        const v2f d = dones  [t * NV2 + n2];
        v2f ret;
        #define STEP(X) { \
            const float nt    = 1.0f - d_next.X; \
            const float delta = fmaf(GAMMA * v_next.X, nt, r.X) - v.X; \
            const float cc    = GL * nt; \
            adv.X = fmaf(cc, adv.X, delta); \
            ret.X = adv.X + v.X; \
            v_next.X = v.X; d_next.X = d.X; }
        STEP(x) STEP(y)
        #undef STEP
        __builtin_nontemporal_store(adv, &out[t * NV2 + n2]);            // advantages
        __builtin_nontemporal_store(ret, &out[(T_LEN + t) * NV2 + n2]);  // returns
    }
}

extern "C" void kernel_launch(void* const* d_in, const int* in_sizes, int n_in,
                              void* d_out, int out_size, void* d_ws, size_t ws_size,
                              hipStream_t stream) {
    const v2f* rewards = (const v2f*)d_in[0];
    const v2f* values  = (const v2f*)d_in[1];
    const v2f* dones   = (const v2f*)d_in[2];
    v2f* out = (v2f*)d_out;

    // Workspace: A | P, each N_CHUNKS*N_ENV fp32 (2 MB each); fully written by
    // K1 before K2 reads them (0xAA poison safe).
    v2f* A = (v2f*)d_ws;
    v2f* P = A + (size_t)N_CHUNKS * NV2;

    const int blk = 256;
    gae_phase1<<<(N_CHUNKS * NV2) / blk, blk, 0, stream>>>(
        rewards, values, dones, A, P);
    gae_phase23<<<(N_CHUNKS * NV2) / blk, blk, 0, stream>>>(
        rewards, values, dones, A, P, out);
}

// Round 7
// 165.258 us; speedup vs baseline: 1.0457x; 1.0457x over previous
//
#include <hip/hip_runtime.h>

// GAE scan: T=2048, N=4096, fp32. Chunked linear-recurrence scan, 3 kernels:
//   K1 : per-(chunk, env2) compose chunk affine (A,P): adv_top = P + A*adv_in
//   K1b: per-(group, env2) compose 8 chunk affines -> group affine (GA,GP)
//   K2 : per-(chunk, env2): hierarchical look-back (<=7 chunk steps + <=15
//        group steps, avg ~11 vs flat avg ~64 -> cache traffic 266->46 MB),
//        then replay the chunk writing advantages and returns.
// R6 lesson: occupancy 6%->27% left phase23 pinned at 41 us / 2.9 TB/s ->
// bottleneck is the O(C^2) look-back's L2/L3 traffic, not latency. This
// version attacks the traffic directly.

#define T_LEN    2048
#define N_ENV    4096
#define NV2      (N_ENV / 2)          // 2048 float2 columns
#define N_CHUNKS 128
#define CHUNK_L  (T_LEN / N_CHUNKS)   // 16
#define GRP_SZ   8
#define N_GRPS   (N_CHUNKS / GRP_SZ)  // 16

typedef float v2f __attribute__((ext_vector_type(2)));

static constexpr float GAMMA = 0.99f;
static constexpr float GL    = 0.99f * 0.95f;   // gamma * gae_lambda

__global__ __launch_bounds__(256) void gae_phase1(
    const v2f* __restrict__ rewards,   // [T_LEN][NV2]
    const v2f* __restrict__ values,
    const v2f* __restrict__ dones,
    v2f* __restrict__ Aout,            // [N_CHUNKS][NV2]
    v2f* __restrict__ Pout)
{
    const int idx = blockIdx.x * blockDim.x + threadIdx.x;   // c*NV2 + n2
    const int n2 = idx & (NV2 - 1);
    const int c  = idx >> 11;
    const int t_hi = c * CHUNK_L + (CHUNK_L - 1);

    v2f v_next, d_next;
    if (c == N_CHUNKS - 1) {
        v_next = (v2f)(0.f, 0.f);
        d_next = (v2f)(1.f, 1.f);
    } else {
        v_next = values[(t_hi + 1) * NV2 + n2];
        d_next = dones [(t_hi + 1) * NV2 + n2];
    }

    v2f A = (v2f)(1.f, 1.f);
    v2f P = (v2f)(0.f, 0.f);

    #pragma unroll
    for (int i = 0; i < CHUNK_L; ++i) {
        const int t = t_hi - i;
        const v2f r = rewards[t * NV2 + n2];
        const v2f v = values [t * NV2 + n2];
        const v2f d = dones  [t * NV2 + n2];
        #define STEP(X) { \
            const float nt    = 1.0f - d_next.X; \
            const float delta = fmaf(GAMMA * v_next.X, nt, r.X) - v.X; \
            const float cc    = GL * nt; \
            P.X = fmaf(cc, P.X, delta); \
            A.X = cc * A.X; \
            v_next.X = v.X; d_next.X = d.X; }
        STEP(x) STEP(y)
        #undef STEP
    }
    Aout[idx] = A;
    Pout[idx] = P;
}

// Compose the 8 chunk affines of each group into one group affine.
// Iterating c2 = hi..lo: GP <- fma(A[c2], GP, P[c2]); GA <- A[c2]*GA
// gives g(x) = GP + GA*x == f_lo(f_{lo+1}(...f_hi(x))).
__global__ __launch_bounds__(256) void gae_phase1b(
    const v2f* __restrict__ Ain,    // [N_CHUNKS][NV2]
    const v2f* __restrict__ Pin,
    v2f* __restrict__ GAout,        // [N_GRPS][NV2]
    v2f* __restrict__ GPout)
{
    const int idx = blockIdx.x * blockDim.x + threadIdx.x;   // g*NV2 + n2
    const int n2 = idx & (NV2 - 1);
    const int g  = idx >> 11;
    const int hi = g * GRP_SZ + (GRP_SZ - 1);

    v2f GA = (v2f)(1.f, 1.f);
    v2f GP = (v2f)(0.f, 0.f);
    #pragma unroll
    for (int i = 0; i < GRP_SZ; ++i) {
        const int c2 = hi - i;
        const v2f a = Ain[c2 * NV2 + n2];
        const v2f p = Pin[c2 * NV2 + n2];
        GP.x = fmaf(a.x, GP.x, p.x);
        GP.y = fmaf(a.y, GP.y, p.y);
        GA.x = a.x * GA.x;
        GA.y = a.y * GA.y;
    }
    GAout[idx] = GA;
    GPout[idx] = GP;
}

__global__ __launch_bounds__(256) void gae_phase23(
    const v2f* __restrict__ rewards,
    const v2f* __restrict__ values,
    const v2f* __restrict__ dones,
    const v2f* __restrict__ Ain,    // [N_CHUNKS][NV2]
    const v2f* __restrict__ Pin,
    const v2f* __restrict__ GAin,   // [N_GRPS][NV2]
    const v2f* __restrict__ GPin,
    v2f* __restrict__ out)          // [2*T_LEN][NV2]: advantages then returns
{
    const int idx = blockIdx.x * blockDim.x + threadIdx.x;
    const int n2 = idx & (NV2 - 1);
    const int c  = idx >> 11;
    const int g  = c / GRP_SZ;
    const int gend = g * GRP_SZ + (GRP_SZ - 1);
    const int t_hi = c * CHUNK_L + (CHUNK_L - 1);

    // Hierarchical look-back: b = f_{c+1}∘...∘f_{127}(0).
    // Apply whole groups 15..g+1 (top-down), then chunks gend..c+1.
    v2f adv = (v2f)(0.f, 0.f);
    for (int g2 = N_GRPS - 1; g2 > g; --g2) {
        const v2f a = GAin[g2 * NV2 + n2];
        const v2f p = GPin[g2 * NV2 + n2];
        adv.x = fmaf(a.x, adv.x, p.x);
        adv.y = fmaf(a.y, adv.y, p.y);
    }
    for (int c2 = gend; c2 > c; --c2) {
        const v2f a = Ain[c2 * NV2 + n2];
        const v2f p = Pin[c2 * NV2 + n2];
        adv.x = fmaf(a.x, adv.x, p.x);
        adv.y = fmaf(a.y, adv.y, p.y);
    }

    v2f v_next, d_next;
    if (c == N_CHUNKS - 1) {
        v_next = (v2f)(0.f, 0.f);
        d_next = (v2f)(1.f, 1.f);
    } else {
        v_next = values[(t_hi + 1) * NV2 + n2];
        d_next = dones [(t_hi + 1) * NV2 + n2];
    }

    #pragma unroll
    for (int i = 0; i < CHUNK_L; ++i) {
        const int t = t_hi - i;
        const v2f r = rewards[t * NV2 + n2];
        const v2f v = values [t * NV2 + n2];
        const v2f d = dones  [t * NV2 + n2];
        v2f ret;
        #define STEP(X) { \
            const float nt    = 1.0f - d_next.X; \
            const float delta = fmaf(GAMMA * v_next.X, nt, r.X) - v.X; \
            const float cc    = GL * nt; \
            adv.X = fmaf(cc, adv.X, delta); \
            ret.X = adv.X + v.X; \
            v_next.X = v.X; d_next.X = d.X; }
        STEP(x) STEP(y)
        #undef STEP
        __builtin_nontemporal_store(adv, &out[t * NV2 + n2]);            // advantages
        __builtin_nontemporal_store(ret, &out[(T_LEN + t) * NV2 + n2]);  // returns
    }
}

extern "C" void kernel_launch(void* const* d_in, const int* in_sizes, int n_in,
                              void* d_out, int out_size, void* d_ws, size_t ws_size,
                              hipStream_t stream) {
    const v2f* rewards = (const v2f*)d_in[0];
    const v2f* values  = (const v2f*)d_in[1];
    const v2f* dones   = (const v2f*)d_in[2];
    v2f* out = (v2f*)d_out;

    // Workspace: A | P (2 MB each) | GA | GP (256 KB each); all fully written
    // before read every launch (0xAA poison safe).
    v2f* A  = (v2f*)d_ws;
    v2f* P  = A  + (size_t)N_CHUNKS * NV2;
    v2f* GA = P  + (size_t)N_CHUNKS * NV2;
    v2f* GP = GA + (size_t)N_GRPS  * NV2;

    const int blk = 256;
    gae_phase1<<<(N_CHUNKS * NV2) / blk, blk, 0, stream>>>(
        rewards, values, dones, A, P);
    gae_phase1b<<<(N_GRPS * NV2) / blk, blk, 0, stream>>>(A, P, GA, GP);
    gae_phase23<<<(N_CHUNKS * NV2) / blk, blk, 0, stream>>>(
        rewards, values, dones, A, P, GA, GP, out);
}